// Round 14
// baseline (162.959 us; speedup 1.0000x reference)
//
#include <hip/hip_runtime.h>

constexpr int H = 128;
constexpr int CAP = 8192;   // bucket window capacity (mean fill <= 4.3k, sigma ~65)

typedef short bf16x8 __attribute__((ext_vector_type(8)));
typedef float f32x4  __attribute__((ext_vector_type(4)));

__device__ __forceinline__ ushort f2b(float f) {
    uint u = __float_as_uint(f);
    u += 0x7fff + ((u >> 16) & 1);      // round-to-nearest-even
    return (ushort)(u >> 16);
}
__device__ __forceinline__ float b2f(ushort b) {
    return __uint_as_float((uint)b << 16);
}

// ---------------- W pack: frag[s][t0+t][lane][j] = W'[s*32+8*(l/16)+j][t*16+l%16]
// addI != 0 folds +identity into the packed matrix (Wr' = Wr + I).
__device__ __forceinline__ void pack_one(const float* __restrict__ W, int ldw,
                                         int t0, int nct, int nctTot,
                                         ushort* __restrict__ dst, int fgl, int l,
                                         float addI)
{
    int t = fgl % nct, s = fgl / nct;
    int col = t * 16 + (l & 15);
    int kb  = s * 32 + (l >> 4) * 8;
    ushort o[8];
    #pragma unroll
    for (int j = 0; j < 8; ++j) {
        float v = W[(size_t)(kb + j) * ldw + col];
        if (kb + j == col) v += addI;
        o[j] = f2b(v);
    }
    ushort* d = dst + ((size_t)(s * nctTot + t0 + t) * 64 + l) * 8;
    *(uint4*)d = *(uint4*)o;
}

// all weights + zeroing the bucket counters (fg >= 184 region)
__global__ __launch_bounds__(256)
void pack_all_kernel(const float* __restrict__ Wp_u, const float* __restrict__ Wp_i,
                     const float* __restrict__ Wl, const float* __restrict__ Wr,
                     const float* __restrict__ Wh,
                     ushort* __restrict__ pPu, ushort* __restrict__ pPi,
                     ushort* __restrict__ pL0, ushort* __restrict__ pL1a,
                     ushort* __restrict__ pL1b, ushort* __restrict__ pH,
                     int* __restrict__ cntG)
{
    int f = blockIdx.x * 256 + threadIdx.x;
    int fg = f >> 6, l = f & 63;
    if (fg < 32)       pack_one(Wp_u,          128, 0, 8, 8,  pPu,  fg,       l, 0.f);
    else if (fg < 48)  pack_one(Wp_i,          128, 0, 8, 8,  pPi,  fg - 32,  l, 0.f);
    else if (fg < 80)  pack_one(Wl,            128, 0, 8, 16, pL0,  fg - 48,  l, 0.f);
    else if (fg < 112) pack_one(Wr,            128, 8, 8, 16, pL0,  fg - 80,  l, 1.f);
    else if (fg < 144) pack_one(Wl + H * H,    128, 0, 8, 8,  pL1a, fg - 112, l, 0.f);
    else if (fg < 176) pack_one(Wr + H * H,    128, 0, 8, 8,  pL1b, fg - 144, l, 1.f);
    else if (fg < 184) pack_one(Wh,             32, 0, 2, 2,  pH,   fg - 176, l, 0.f);
    else {
        int k = f - 184 * 64;
        if (k < 512) cntG[k] = 0;
    }
}

// ---------------- MFMA GEMM body (A fp32 or bf16; C fp32 or bf16) ----------
template<int K, int NCT, bool ABF16, bool BIAS, bool RELU, bool OBF16>
__device__ __forceinline__ void mfma_gemm_body(
    const void* __restrict__ Av, const ushort* __restrict__ Wp,
    const float* __restrict__ bias, void* __restrict__ Cv, int M, int blk)
{
    constexpr int S   = K / 32;
    constexpr int LDC = NCT * 16;
    const int wave = threadIdx.x >> 6;
    const int lane = threadIdx.x & 63;
    const int row0 = blk * 64 + wave * 16;

    int ar = row0 + (lane & 15);
    if (ar >= M) ar = M - 1;                      // clamp loads; stores guarded
    const bf16x8* W8 = (const bf16x8*)Wp;

    f32x4 acc[NCT];
    #pragma unroll
    for (int t = 0; t < NCT; ++t) acc[t] = (f32x4){0.f, 0.f, 0.f, 0.f};

    #pragma unroll
    for (int s = 0; s < S; ++s) {
        bf16x8 a;
        if constexpr (ABF16) {
            const ushort* arow = (const ushort*)Av + (size_t)ar * K + (lane >> 4) * 8;
            a = *(const bf16x8*)(arow + s * 32);
        } else {
            const float* arow = (const float*)Av + (size_t)ar * K + (lane >> 4) * 8;
            float4 f0 = *(const float4*)(arow + s * 32);
            float4 f1 = *(const float4*)(arow + s * 32 + 4);
            a[0] = (short)f2b(f0.x); a[1] = (short)f2b(f0.y);
            a[2] = (short)f2b(f0.z); a[3] = (short)f2b(f0.w);
            a[4] = (short)f2b(f1.x); a[5] = (short)f2b(f1.y);
            a[6] = (short)f2b(f1.z); a[7] = (short)f2b(f1.w);
        }
        #pragma unroll
        for (int t = 0; t < NCT; ++t) {
            bf16x8 b = W8[(size_t)(s * NCT + t) * 64 + lane];
            acc[t] = __builtin_amdgcn_mfma_f32_16x16x32_bf16(a, b, acc[t], 0, 0, 0);
        }
    }

    const int cg = lane & 15;
    const int rg = (lane >> 4) * 4;
    #pragma unroll
    for (int t = 0; t < NCT; ++t) {
        int col = t * 16 + cg;
        float bb = 0.f;
        if constexpr (BIAS) bb = bias[col];
        #pragma unroll
        for (int r = 0; r < 4; ++r) {
            int row = row0 + rg + r;
            if (row < M) {
                float v = acc[t][r] + bb;
                if constexpr (RELU) v = fmaxf(v, 0.f);
                if constexpr (OBF16)
                    ((ushort*)Cv)[(size_t)row * LDC + col] = f2b(v);
                else
                    ((float*)Cv)[(size_t)row * LDC + col] = v;
            }
        }
    }
}

// ---- layer-0 GEMM with SPLIT outputs: Ya = A@Wl (dense), Yb = A@(Wr+I) (dense)
__device__ __forceinline__ void mfma_gemm_split_body(
    const ushort* __restrict__ A, const ushort* __restrict__ Wp,
    ushort* __restrict__ Ca, ushort* __restrict__ Cb, int M, int blk)
{
    const int wave = threadIdx.x >> 6;
    const int lane = threadIdx.x & 63;
    const int row0 = blk * 64 + wave * 16;

    int ar = row0 + (lane & 15);
    if (ar >= M) ar = M - 1;
    const ushort* arow = A + (size_t)ar * H + (lane >> 4) * 8;
    const bf16x8* W8 = (const bf16x8*)Wp;

    f32x4 acc[16];
    #pragma unroll
    for (int t = 0; t < 16; ++t) acc[t] = (f32x4){0.f, 0.f, 0.f, 0.f};

    #pragma unroll
    for (int s = 0; s < 4; ++s) {
        bf16x8 a = *(const bf16x8*)(arow + s * 32);
        #pragma unroll
        for (int t = 0; t < 16; ++t) {
            bf16x8 b = W8[(size_t)(s * 16 + t) * 64 + lane];
            acc[t] = __builtin_amdgcn_mfma_f32_16x16x32_bf16(a, b, acc[t], 0, 0, 0);
        }
    }

    const int cg = lane & 15;
    const int rg = (lane >> 4) * 4;
    #pragma unroll
    for (int t = 0; t < 16; ++t) {
        ushort* C = (t < 8) ? Ca : Cb;
        int col = (t & 7) * 16 + cg;
        #pragma unroll
        for (int r = 0; r < 4; ++r) {
            int row = row0 + rg + r;
            if (row < M) C[(size_t)row * H + col] = f2b(acc[t][r]);
        }
    }
}

// ---------------- bucket scatter body (4096 edges/block) ----------------
__device__ __forceinline__ void bscatter_body(
    const int* __restrict__ src, const int* __restrict__ dst,
    int* __restrict__ cntG, int* __restrict__ pairs, int E, int blk)
{
    __shared__ int cnt[256];
    __shared__ int basew[256];
    cnt[threadIdx.x] = 0;
    __syncthreads();
    const int i0 = blk * 4096 + threadIdx.x;
    int b[16], lofs[16], pk[16];
    #pragma unroll
    for (int j = 0; j < 16; ++j) {
        int i = i0 + j * 256;
        if (i < E) {
            int d = dst[i];
            b[j] = d >> 8;
            lofs[j] = atomicAdd(&cnt[b[j]], 1);
            pk[j] = src[i] | ((d & 255) << 24);      // src < 2^24
        } else b[j] = -1;
    }
    __syncthreads();
    int c = cnt[threadIdx.x];
    if (c) basew[threadIdx.x] = atomicAdd(&cntG[threadIdx.x], c);
    __syncthreads();
    #pragma unroll
    for (int j = 0; j < 16; ++j)
        if (b[j] >= 0) {
            int pos = basew[b[j]] + lofs[j];
            if (pos < CAP) pairs[(size_t)b[j] * CAP + pos] = pk[j];
        }
}

// fused: [0, 2*ebs4) scatter both sides | [.., +gU+gI) input projections
__global__ __launch_bounds__(256)
void scatter_proj_kernel(const int* __restrict__ iu_src, const int* __restrict__ iu_dst,
                         int* __restrict__ cntGU, int* __restrict__ pairsU,
                         const int* __restrict__ ui_src, const int* __restrict__ ui_dst,
                         int* __restrict__ cntGI, int* __restrict__ pairsI,
                         int E, int ebs4,
                         const float* __restrict__ x_u, const ushort* __restrict__ pPu,
                         const float* __restrict__ bp_u, ushort* __restrict__ hU,
                         int N_U, int gU,
                         const float* __restrict__ x_i, const ushort* __restrict__ pPi,
                         const float* __restrict__ bp_i, ushort* __restrict__ hI, int N_I)
{
    const int b = blockIdx.x;
    if (b < ebs4)
        bscatter_body(iu_src, iu_dst, cntGU, pairsU, E, b);
    else if (b < 2 * ebs4)
        bscatter_body(ui_src, ui_dst, cntGI, pairsI, E, b - ebs4);
    else if (b < 2 * ebs4 + gU)
        mfma_gemm_body<128, 8, false, true, true, true>(x_u, pPu, bp_u, hU, N_U,
                                                        b - 2 * ebs4);
    else
        mfma_gemm_body<64, 8, false, true, true, true>(x_i, pPi, bp_i, hI, N_I,
                                                       b - 2 * ebs4 - gU);
}

// ---------------- bucket fill body: window -> per-node lists + rowBE --------
__device__ __forceinline__ void bfill_body(
    const int* __restrict__ cntG, int2* __restrict__ rowBE,
    int* __restrict__ lists, const int* __restrict__ pairs, int N, int lb)
{
    __shared__ int stage[CAP];
    __shared__ int cnt[256];
    __shared__ int buf[256];
    __shared__ int cur[256];
    const int t = threadIdx.x;
    const int base = lb * CAP;
    const int n = min(cntG[lb], CAP);
    cnt[t] = 0;
    __syncthreads();
    for (int k = t; k < n; k += 256) {
        int v = pairs[(size_t)base + k];
        stage[k] = v;
        atomicAdd(&cnt[(v >> 24) & 255], 1);
    }
    __syncthreads();
    int val = cnt[t];
    buf[t] = val;
    __syncthreads();
    #pragma unroll
    for (int off = 1; off < 256; off <<= 1) {
        int x = (t >= off) ? buf[t - off] : 0;
        __syncthreads();
        buf[t] += x;
        __syncthreads();
    }
    int excl = buf[t] - val;
    int node = lb * 256 + t;
    if (node < N) rowBE[node] = make_int2(base + excl, base + excl + val);
    cur[t] = excl;
    __syncthreads();
    for (int k = t; k < n; k += 256) {
        int v = stage[k];
        int dl = (v >> 24) & 255;
        int pos = base + atomicAdd(&cur[dl], 1);
        lists[pos] = v & 0xFFFFFF;
    }
}

// fused: [0, nbkU+nbkI) bucket fill | [.., +gU+gI) layer-0 split GEMM
__global__ __launch_bounds__(256)
void fill_gemm_kernel(const int* __restrict__ cntGU, int2* __restrict__ rowBEU,
                      int* __restrict__ listsU, const int* __restrict__ pairsU,
                      int N_U, int nbkU,
                      const int* __restrict__ cntGI, int2* __restrict__ rowBEI,
                      int* __restrict__ listsI, const int* __restrict__ pairsI,
                      int N_I, int nbkI,
                      const ushort* __restrict__ hU, const ushort* __restrict__ Wp,
                      ushort* __restrict__ Ya_u, ushort* __restrict__ Yb_u, int gU,
                      const ushort* __restrict__ hI,
                      ushort* __restrict__ Ya_i, ushort* __restrict__ Yb_i)
{
    const int b = blockIdx.x;
    if (b < nbkU)
        bfill_body(cntGU, rowBEU, listsU, pairsU, N_U, b);
    else if (b < nbkU + nbkI)
        bfill_body(cntGI, rowBEI, listsI, pairsI, N_I, b - nbkU);
    else if (b < nbkU + nbkI + gU)
        mfma_gemm_split_body(hU, Wp, Ya_u, Yb_u, N_U, b - nbkU - nbkI);
    else
        mfma_gemm_split_body(hI, Wp, Ya_i, Yb_i, N_I, b - nbkU - nbkI - gU);
}

// layer-1 I-side GEMM: Yi8 = hI @ Wl1 (the only live I-half)
__global__ __launch_bounds__(256)
void gemmI_kernel(const ushort* __restrict__ hI, const ushort* __restrict__ pA,
                  ushort* __restrict__ Yi8, int N_I)
{
    mfma_gemm_body<128, 8, true, false, false, true>(hI, pA, nullptr, Yi8, N_I,
                                                     blockIdx.x);
}

// ---------------- fused gather + SAGE update -----------------
// 1 wave per node; 4 groups x 16 lanes; lane owns 8 cols (uint4 = 16 B);
// 8 edges in flight. Combine: shfl_xor 16, 32. All tables dense [N,128].
template<bool BN, bool AGG>
__device__ __forceinline__ void gather_body(
    const ushort* __restrict__ Ysrc, const ushort* __restrict__ Ydst,
    ushort* __restrict__ hB,
    const int2* __restrict__ rowBE, const int* __restrict__ lists,
    const float* __restrict__ bl, const float* __restrict__ gamma,
    const float* __restrict__ beta, const float* __restrict__ mean,
    const float* __restrict__ var, int N, int blk)
{
    const int node = blk * 4 + (threadIdx.x >> 6);
    if (node >= N) return;
    const int lane = threadIdx.x & 63;
    const int grp  = lane >> 4;
    const int c8   = (lane & 15) * 8;

    const int2 be = rowBE[node];
    const int beg = be.x, end = be.y;

    float s[8] = {0.f, 0.f, 0.f, 0.f, 0.f, 0.f, 0.f, 0.f};
    int e = beg + grp;
    for (; e + 4 < end; e += 8) {                 // 8 edges in flight per wave
        int s0 = lists[e], s1 = lists[e + 4];
        uint4 v0 = *(const uint4*)&Ysrc[(size_t)s0 * H + c8];
        uint4 v1 = *(const uint4*)&Ysrc[(size_t)s1 * H + c8];
        s[0] += b2f((ushort)v0.x) + b2f((ushort)v1.x);
        s[1] += b2f((ushort)(v0.x >> 16)) + b2f((ushort)(v1.x >> 16));
        s[2] += b2f((ushort)v0.y) + b2f((ushort)v1.y);
        s[3] += b2f((ushort)(v0.y >> 16)) + b2f((ushort)(v1.y >> 16));
        s[4] += b2f((ushort)v0.z) + b2f((ushort)v1.z);
        s[5] += b2f((ushort)(v0.z >> 16)) + b2f((ushort)(v1.z >> 16));
        s[6] += b2f((ushort)v0.w) + b2f((ushort)v1.w);
        s[7] += b2f((ushort)(v0.w >> 16)) + b2f((ushort)(v1.w >> 16));
    }
    if (e < end) {
        int s0 = lists[e];
        uint4 v0 = *(const uint4*)&Ysrc[(size_t)s0 * H + c8];
        s[0] += b2f((ushort)v0.x); s[1] += b2f((ushort)(v0.x >> 16));
        s[2] += b2f((ushort)v0.y); s[3] += b2f((ushort)(v0.y >> 16));
        s[4] += b2f((ushort)v0.z); s[5] += b2f((ushort)(v0.z >> 16));
        s[6] += b2f((ushort)v0.w); s[7] += b2f((ushort)(v0.w >> 16));
    }
    #pragma unroll
    for (int j = 0; j < 8; ++j) {
        s[j] += __shfl_xor(s[j], 16, 64);
        s[j] += __shfl_xor(s[j], 32, 64);
    }
    if (grp != 0) return;                          // lanes 0-15 finish the node
    const int deg = end - beg;
    const float sc = (deg > 0) ? 1.0f / (float)deg : 0.f;

    if constexpr (AGG) {
        ushort hb[8];
        #pragma unroll
        for (int j = 0; j < 8; ++j) hb[j] = f2b(s[j] * sc);
        *(uint4*)&hB[(size_t)node * H + c8] = *(uint4*)hb;
        return;
    } else {
        uint4 yv = *(const uint4*)&Ydst[(size_t)node * H + c8];
        float y[8] = { b2f((ushort)yv.x), b2f((ushort)(yv.x >> 16)),
                       b2f((ushort)yv.y), b2f((ushort)(yv.y >> 16)),
                       b2f((ushort)yv.z), b2f((ushort)(yv.z >> 16)),
                       b2f((ushort)yv.w), b2f((ushort)(yv.w >> 16)) };
        float o[8];
        #pragma unroll
        for (int j = 0; j < 8; ++j) {
            float u = (s[j] * sc + y[j] + bl[c8 + j]) * 0.5f;
            if constexpr (BN)
                u = (u - mean[c8 + j]) * rsqrtf(var[c8 + j] + 1e-5f) * gamma[c8 + j]
                    + beta[c8 + j];
            o[j] = fmaxf(u, 0.f);
        }
        ushort hb[8];
        #pragma unroll
        for (int j = 0; j < 8; ++j) hb[j] = f2b(o[j]);
        *(uint4*)&hB[(size_t)node * H + c8] = *(uint4*)hb;
    }
}

// layer-0 gather: both sides (dense Ya src, dense Yb self)
__global__ __launch_bounds__(256)
void gather2_kernel(const ushort* __restrict__ Ya_i, const ushort* __restrict__ Yb_u,
                    ushort* __restrict__ hU,
                    const int2* __restrict__ beU, const int* __restrict__ liU,
                    const float* __restrict__ bl, const float* __restrict__ gamma,
                    const float* __restrict__ beta, const float* __restrict__ mean,
                    const float* __restrict__ var, int N_U, int nbU,
                    const ushort* __restrict__ Ya_u, const ushort* __restrict__ Yb_i,
                    ushort* __restrict__ hI,
                    const int2* __restrict__ beI, const int* __restrict__ liI, int N_I)
{
    if ((int)blockIdx.x < nbU)
        gather_body<true, false>(Ya_i, Yb_u, hU, beU, liU,
                                 bl, gamma, beta, mean, var, N_U, blockIdx.x);
    else
        gather_body<false, false>(Ya_u, Yb_i, hI, beI, liI,
                                  bl, gamma, beta, mean, var, N_I,
                                  blockIdx.x - nbU);
}

// layer-1 gather: U side only, agg-only output (bf16 mean of Yi8 rows)
__global__ __launch_bounds__(256)
void gather1agg_kernel(const ushort* __restrict__ Yi8, ushort* __restrict__ aggU,
                       const int2* __restrict__ beU, const int* __restrict__ liU,
                       int N_U)
{
    gather_body<false, true>(Yi8, nullptr, aggU, beU, liU,
                             nullptr, nullptr, nullptr, nullptr, nullptr,
                             N_U, blockIdx.x);
}

// ---------------- tail: {hU@(Wr1+I) + Agg + bl -> BN -> relu} -> out1,
//                  then relu-tile @ Wh + bh -> out0, all in one kernel --------
__global__ __launch_bounds__(256)
void tail_kernel(const ushort* __restrict__ hU, const ushort* __restrict__ pWr1,
                 const ushort* __restrict__ aggU,
                 const float* __restrict__ bl1, const float* __restrict__ gamma1,
                 const float* __restrict__ beta1, const float* __restrict__ mean1,
                 const float* __restrict__ var1,
                 const ushort* __restrict__ pH, const float* __restrict__ bh,
                 float* __restrict__ out0, float* __restrict__ out1, int M)
{
    constexpr int LDT = H + 8;            // padded ushort stride (bank shift 4)
    __shared__ ushort T[64 * LDT];        // relu output tile (A for head MFMA)
    __shared__ ushort AG[64 * LDT];       // staged agg tile
    const int wave  = threadIdx.x >> 6;
    const int lane  = threadIdx.x & 63;
    const int row0g = blockIdx.x * 64;
    const int row0  = row0g + wave * 16;

    // stage Agg tile (64 x 128 bf16) coalesced
    #pragma unroll
    for (int i = 0; i < 4; ++i) {
        int idx = i * 256 + threadIdx.x;          // uint4 index; 1024 total
        int r = idx >> 4;
        int c = (idx & 15) * 8;
        int gr = row0g + r; if (gr >= M) gr = M - 1;
        uint4 v = *(const uint4*)&aggU[(size_t)gr * H + c];
        *(uint4*)&AG[r * LDT + c] = v;
    }

    // MFMA 1: hU @ (Wr1 + I), NCT=8
    int ar = row0 + (lane & 15); if (ar >= M) ar = M - 1;
    const ushort* arow = hU + (size_t)ar * H + (lane >> 4) * 8;
    const bf16x8* W8 = (const bf16x8*)pWr1;
    f32x4 acc[8];
    #pragma unroll
    for (int t = 0; t < 8; ++t) acc[t] = (f32x4){0.f, 0.f, 0.f, 0.f};
    #pragma unroll
    for (int s = 0; s < 4; ++s) {
        bf16x8 a = *(const bf16x8*)(arow + s * 32);
        #pragma unroll
        for (int t = 0; t < 8; ++t) {
            bf16x8 b = W8[(size_t)(s * 8 + t) * 64 + lane];
            acc[t] = __builtin_amdgcn_mfma_f32_16x16x32_bf16(a, b, acc[t], 0, 0, 0);
        }
    }
    __syncthreads();                      // AG staged

    const int cg = lane & 15;
    const int rg = (lane >> 4) * 4;
    #pragma unroll
    for (int t = 0; t < 8; ++t) {
        int col = t * 16 + cg;
        float rs = rsqrtf(var1[col] + 1e-5f) * gamma1[col];
        #pragma unroll
        for (int r = 0; r < 4; ++r) {
            int lr = wave * 16 + rg + r;
            int grow = row0 + rg + r;
            float u = (acc[t][r] + b2f(AG[lr * LDT + col]) + bl1[col]) * 0.5f;
            u = (u - mean1[col]) * rs + beta1[col];
            float o = fmaxf(u, 0.f);
            T[lr * LDT + col] = f2b(o);
            if (grow < M) out1[(size_t)grow * H + col] = o;
        }
    }
    __syncthreads();                      // T complete

    // MFMA 2: T @ Wh (NCT=2)
    const bf16x8* H8 = (const bf16x8*)pH;
    f32x4 acc2[2];
    acc2[0] = (f32x4){0.f, 0.f, 0.f, 0.f};
    acc2[1] = (f32x4){0.f, 0.f, 0.f, 0.f};
    const ushort* trow = &T[(wave * 16 + (lane & 15)) * LDT + (lane >> 4) * 8];
    #pragma unroll
    for (int s = 0; s < 4; ++s) {
        bf16x8 a = *(const bf16x8*)(trow + s * 32);
        #pragma unroll
        for (int t = 0; t < 2; ++t) {
            bf16x8 b = H8[(size_t)(s * 2 + t) * 64 + lane];
            acc2[t] = __builtin_amdgcn_mfma_f32_16x16x32_bf16(a, b, acc2[t], 0, 0, 0);
        }
    }
    #pragma unroll
    for (int t = 0; t < 2; ++t) {
        int col = t * 16 + cg;
        float bb = bh[col];
        #pragma unroll
        for (int r = 0; r < 4; ++r) {
            int grow = row0 + rg + r;
            if (grow < M) out0[(size_t)grow * 32 + col] = acc2[t][r] + bb;
        }
    }
}

extern "C" void kernel_launch(void* const* d_in, const int* in_sizes, int n_in,
                              void* d_out, int out_size, void* d_ws, size_t ws_size,
                              hipStream_t stream)
{
    const float* x_u   = (const float*)d_in[0];
    const float* x_i   = (const float*)d_in[1];
    const int*   iu_src = (const int*)d_in[2];
    const int*   iu_dst = (const int*)d_in[3];
    const int*   ui_src = (const int*)d_in[4];
    const int*   ui_dst = (const int*)d_in[5];
    const float* Wp_u  = (const float*)d_in[6];
    const float* bp_u  = (const float*)d_in[7];
    const float* Wp_i  = (const float*)d_in[8];
    const float* bp_i  = (const float*)d_in[9];
    const float* Wl    = (const float*)d_in[10];
    const float* bl    = (const float*)d_in[11];
    const float* Wr    = (const float*)d_in[12];
    const float* gamma = (const float*)d_in[13];
    const float* beta  = (const float*)d_in[14];
    const float* mean  = (const float*)d_in[15];
    const float* var   = (const float*)d_in[16];
    const float* Wh    = (const float*)d_in[17];
    const float* bh    = (const float*)d_in[18];

    const int N_U = in_sizes[0] / 128;      // 50000
    const int N_I = in_sizes[1] / 64;       // 30000
    const int E   = in_sizes[2];            // 500000
    const int OUT = 32;

    float* out  = (float*)d_out;
    float* out1 = out + (size_t)N_U * OUT;

    const int nbkU = (N_U + 255) / 256;     // buckets
    const int nbkI = (N_I + 255) / 256;

    // workspace layout (all Y tables dense [N,128] bf16)
    ushort* hU   = (ushort*)d_ws;                     // [N_U,128]
    ushort* hI   = hU + (size_t)N_U * H;              // [N_I,128]
    ushort* Ya_u = hI + (size_t)N_I * H;              // [N_U,128]  h_u@Wl0   (gathered by I)
    ushort* Yb_u = Ya_u + (size_t)N_U * H;            // [N_U,128]  h_u@(Wr0+I) / aggU (l1)
    ushort* Ya_i = Yb_u + (size_t)N_U * H;            // [N_I,128]  h_i@Wl0 (gathered by U) / Yi8 (l1)
    ushort* Yb_i = Ya_i + (size_t)N_I * H;            // [N_I,128]  h_i@(Wr0+I)
    int*    ip   = (int*)(((uintptr_t)(Yb_i + (size_t)N_I * H) + 15) & ~(uintptr_t)15);
    int2* rowBEU = (int2*)ip;        ip += 2 * N_U;
    int2* rowBEI = (int2*)ip;        ip += 2 * N_I;
    int* listsU  = ip;               ip += nbkU * CAP;
    int* listsI  = ip;               ip += nbkI * CAP;
    int* pairsU  = ip;               ip += nbkU * CAP;
    int* pairsI  = ip;               ip += nbkI * CAP;
    int* cntGU   = ip;               ip += 256;
    int* cntGI   = ip;               ip += 256;
    // packed weights (bf16), 16B-aligned
    ushort* up   = (ushort*)(((uintptr_t)ip + 15) & ~(uintptr_t)15);
    ushort* pPu  = up;               up += 4 * 8  * 64 * 8;   // K=128, NCT=8
    ushort* pPi  = up;               up += 2 * 8  * 64 * 8;   // K=64,  NCT=8
    ushort* pL0  = up;               up += 4 * 16 * 64 * 8;   // [Wl0 | Wr0+I]
    ushort* pL1a = up;               up += 4 * 8  * 64 * 8;   // Wl1
    ushort* pL1b = up;               up += 4 * 8  * 64 * 8;   // Wr1 + I
    ushort* pH   = up;               up += 4 * 2  * 64 * 8;   // Wh

    const int ebs4 = (E + 4095) / 4096;     // scatter blocks per side
    const int gU   = (N_U + 63) / 64;       // gemm blocks
    const int gI   = (N_I + 63) / 64;
    const int aU   = (N_U + 3) / 4;         // gather blocks
    const int aI   = (N_I + 3) / 4;

    // ---- pack weights (+ zero bucket counters; cntGU/cntGI contiguous) ----
    pack_all_kernel<<<48, 256, 0, stream>>>(
        Wp_u, Wp_i, Wl, Wr, Wh, pPu, pPi, pL0, pL1a, pL1b, pH, cntGU);

    // ---- fused: bucket-scatter (both sides) || input projections ----
    scatter_proj_kernel<<<2 * ebs4 + gU + gI, 256, 0, stream>>>(
        iu_src, iu_dst, cntGU, pairsU,
        ui_src, ui_dst, cntGI, pairsI, E, ebs4,
        x_u, pPu, bp_u, hU, N_U, gU,
        x_i, pPi, bp_i, hI, N_I);

    // ---- fused: bucket-fill (both sides) || layer-0 split GEMM ----
    fill_gemm_kernel<<<nbkU + nbkI + gU + gI, 256, 0, stream>>>(
        cntGU, rowBEU, listsU, pairsU, N_U, nbkU,
        cntGI, rowBEI, listsI, pairsI, N_I, nbkI,
        hU, pL0, Ya_u, Yb_u, gU, hI, Ya_i, Yb_i);

    // ---- layer 0: gather both sides (dense src tables) ----
    gather2_kernel<<<aU + aI, 256, 0, stream>>>(
        Ya_i, Yb_u, hU, rowBEU, listsU,
        bl, gamma, beta, mean, var, N_U, aU,
        Ya_u, Yb_i, hI, rowBEI, listsI, N_I);

    // ---- layer 1: Yi8 = hI @ Wl1 (only live I-half; reuses Ya_i) ----
    gemmI_kernel<<<gI, 256, 0, stream>>>(hI, pL1a, Ya_i, N_I);

    // ---- layer 1: U-side agg only -> bf16 aggU (reuses Yb_u) ----
    gather1agg_kernel<<<aU, 256, 0, stream>>>(Ya_i, Yb_u, rowBEU, listsU, N_U);

    // ---- tail: hU@(Wr1+I) + Agg + bl -> BN -> relu -> out1; @Wh+bh -> out0 ----
    tail_kernel<<<gU, 256, 0, stream>>>(
        hU, pL1b, Yb_u,
        bl + H, gamma + H, beta + H, mean + H, var + H,
        pH, bh, out, out1, N_U);
}

// Round 16
// 162.516 us; speedup vs baseline: 1.0027x; 1.0027x over previous
//
#include <hip/hip_runtime.h>

constexpr int H = 128;
constexpr int CAP = 8192;   // bucket window capacity (mean fill <= 4.3k, sigma ~65)

typedef short bf16x8 __attribute__((ext_vector_type(8)));
typedef float f32x4  __attribute__((ext_vector_type(4)));

__device__ __forceinline__ ushort f2b(float f) {
    uint u = __float_as_uint(f);
    u += 0x7fff + ((u >> 16) & 1);      // round-to-nearest-even
    return (ushort)(u >> 16);
}
__device__ __forceinline__ float b2f(ushort b) {
    return __uint_as_float((uint)b << 16);
}

// accumulate 2 bf16 (packed in w) into even/odd f32 accumulators.
// NOTE: fdot2_f32_bf16 builtin gave wrong results on gfx950 (R15 fail) — plain path.
__device__ __forceinline__ void acc2(float& se, float& so, uint w) {
    se += __uint_as_float(w << 16);
    so += __uint_as_float(w & 0xFFFF0000u);
}

// ---------------- W pack: frag[s][t0+t][lane][j] = W'[s*32+8*(l/16)+j][t*16+l%16]
__device__ __forceinline__ void pack_one(const float* __restrict__ W, int ldw,
                                         int t0, int nct, int nctTot,
                                         ushort* __restrict__ dst, int fgl, int l,
                                         float addI)
{
    int t = fgl % nct, s = fgl / nct;
    int col = t * 16 + (l & 15);
    int kb  = s * 32 + (l >> 4) * 8;
    ushort o[8];
    #pragma unroll
    for (int j = 0; j < 8; ++j) {
        float v = W[(size_t)(kb + j) * ldw + col];
        if (kb + j == col) v += addI;
        o[j] = f2b(v);
    }
    ushort* d = dst + ((size_t)(s * nctTot + t0 + t) * 64 + l) * 8;
    *(uint4*)d = *(uint4*)o;
}

// all weights + cntG zero + folded BN/bias tables:
//   bnS[t*128+c], bnB[t*128+c]; t=0: layer0 U (BN), t=1: layer0 I (no BN),
//   t=2: layer1 U (BN). update: o = relu((s*sc + y) * S2 + B2).
__global__ __launch_bounds__(256)
void pack_all_kernel(const float* __restrict__ Wp_u, const float* __restrict__ Wp_i,
                     const float* __restrict__ Wl, const float* __restrict__ Wr,
                     const float* __restrict__ Wh,
                     const float* __restrict__ bl, const float* __restrict__ gamma,
                     const float* __restrict__ beta, const float* __restrict__ mean,
                     const float* __restrict__ var,
                     ushort* __restrict__ pPu, ushort* __restrict__ pPi,
                     ushort* __restrict__ pL0, ushort* __restrict__ pL1a,
                     ushort* __restrict__ pL1b, ushort* __restrict__ pH,
                     int* __restrict__ cntG, float* __restrict__ bnS,
                     float* __restrict__ bnB)
{
    int f = blockIdx.x * 256 + threadIdx.x;
    int fg = f >> 6, l = f & 63;
    if (fg < 32)       pack_one(Wp_u,          128, 0, 8, 8,  pPu,  fg,       l, 0.f);
    else if (fg < 48)  pack_one(Wp_i,          128, 0, 8, 8,  pPi,  fg - 32,  l, 0.f);
    else if (fg < 80)  pack_one(Wl,            128, 0, 8, 16, pL0,  fg - 48,  l, 0.f);
    else if (fg < 112) pack_one(Wr,            128, 8, 8, 16, pL0,  fg - 80,  l, 1.f);
    else if (fg < 144) pack_one(Wl + H * H,    128, 0, 8, 8,  pL1a, fg - 112, l, 0.f);
    else if (fg < 176) pack_one(Wr + H * H,    128, 0, 8, 8,  pL1b, fg - 144, l, 1.f);
    else if (fg < 184) pack_one(Wh,             32, 0, 2, 2,  pH,   fg - 176, l, 0.f);
    else {
        int k = f - 184 * 64;
        if (k < 512) cntG[k] = 0;
        else if (k < 512 + 384) {
            int idx = k - 512;
            int t = idx >> 7, c = idx & 127;
            if (t == 1) {
                bnS[128 + c] = 0.5f;
                bnB[128 + c] = 0.5f * bl[c];
            } else {
                int o = (t == 0) ? 0 : H;     // layer offset
                float S = rsqrtf(var[o + c] + 1e-5f) * gamma[o + c];
                bnS[t * 128 + c] = 0.5f * S;
                bnB[t * 128 + c] = beta[o + c] - mean[o + c] * S + 0.5f * bl[o + c] * S;
            }
        }
    }
}

// ---------------- MFMA GEMM body (A fp32 or bf16; C fp32 or bf16) ----------
template<int K, int NCT, bool ABF16, bool BIAS, bool RELU, bool OBF16>
__device__ __forceinline__ void mfma_gemm_body(
    const void* __restrict__ Av, const ushort* __restrict__ Wp,
    const float* __restrict__ bias, void* __restrict__ Cv, int M, int blk)
{
    constexpr int S   = K / 32;
    constexpr int LDC = NCT * 16;
    const int wave = threadIdx.x >> 6;
    const int lane = threadIdx.x & 63;
    const int row0 = blk * 64 + wave * 16;

    int ar = row0 + (lane & 15);
    if (ar >= M) ar = M - 1;                      // clamp loads; stores guarded
    const bf16x8* W8 = (const bf16x8*)Wp;

    f32x4 acc[NCT];
    #pragma unroll
    for (int t = 0; t < NCT; ++t) acc[t] = (f32x4){0.f, 0.f, 0.f, 0.f};

    #pragma unroll
    for (int s = 0; s < S; ++s) {
        bf16x8 a;
        if constexpr (ABF16) {
            const ushort* arow = (const ushort*)Av + (size_t)ar * K + (lane >> 4) * 8;
            a = *(const bf16x8*)(arow + s * 32);
        } else {
            const float* arow = (const float*)Av + (size_t)ar * K + (lane >> 4) * 8;
            float4 f0 = *(const float4*)(arow + s * 32);
            float4 f1 = *(const float4*)(arow + s * 32 + 4);
            a[0] = (short)f2b(f0.x); a[1] = (short)f2b(f0.y);
            a[2] = (short)f2b(f0.z); a[3] = (short)f2b(f0.w);
            a[4] = (short)f2b(f1.x); a[5] = (short)f2b(f1.y);
            a[6] = (short)f2b(f1.z); a[7] = (short)f2b(f1.w);
        }
        #pragma unroll
        for (int t = 0; t < NCT; ++t) {
            bf16x8 b = W8[(size_t)(s * NCT + t) * 64 + lane];
            acc[t] = __builtin_amdgcn_mfma_f32_16x16x32_bf16(a, b, acc[t], 0, 0, 0);
        }
    }

    const int cg = lane & 15;
    const int rg = (lane >> 4) * 4;
    #pragma unroll
    for (int t = 0; t < NCT; ++t) {
        int col = t * 16 + cg;
        float bb = 0.f;
        if constexpr (BIAS) bb = bias[col];
        #pragma unroll
        for (int r = 0; r < 4; ++r) {
            int row = row0 + rg + r;
            if (row < M) {
                float v = acc[t][r] + bb;
                if constexpr (RELU) v = fmaxf(v, 0.f);
                if constexpr (OBF16)
                    ((ushort*)Cv)[(size_t)row * LDC + col] = f2b(v);
                else
                    ((float*)Cv)[(size_t)row * LDC + col] = v;
            }
        }
    }
}

// ---- layer-0 GEMM with SPLIT outputs: Ya = A@Wl (dense), Yb = A@(Wr+I) -----
__device__ __forceinline__ void mfma_gemm_split_body(
    const ushort* __restrict__ A, const ushort* __restrict__ Wp,
    ushort* __restrict__ Ca, ushort* __restrict__ Cb, int M, int blk)
{
    const int wave = threadIdx.x >> 6;
    const int lane = threadIdx.x & 63;
    const int row0 = blk * 64 + wave * 16;

    int ar = row0 + (lane & 15);
    if (ar >= M) ar = M - 1;
    const ushort* arow = A + (size_t)ar * H + (lane >> 4) * 8;
    const bf16x8* W8 = (const bf16x8*)Wp;

    f32x4 acc[16];
    #pragma unroll
    for (int t = 0; t < 16; ++t) acc[t] = (f32x4){0.f, 0.f, 0.f, 0.f};

    #pragma unroll
    for (int s = 0; s < 4; ++s) {
        bf16x8 a = *(const bf16x8*)(arow + s * 32);
        #pragma unroll
        for (int t = 0; t < 16; ++t) {
            bf16x8 b = W8[(size_t)(s * 16 + t) * 64 + lane];
            acc[t] = __builtin_amdgcn_mfma_f32_16x16x32_bf16(a, b, acc[t], 0, 0, 0);
        }
    }

    const int cg = lane & 15;
    const int rg = (lane >> 4) * 4;
    #pragma unroll
    for (int t = 0; t < 16; ++t) {
        ushort* C = (t < 8) ? Ca : Cb;
        int col = (t & 7) * 16 + cg;
        #pragma unroll
        for (int r = 0; r < 4; ++r) {
            int row = row0 + rg + r;
            if (row < M) C[(size_t)row * H + col] = f2b(acc[t][r]);
        }
    }
}

// ---------------- bucket scatter body (4096 edges/block) ----------------
__device__ __forceinline__ void bscatter_body(
    const int* __restrict__ src, const int* __restrict__ dst,
    int* __restrict__ cntG, int* __restrict__ pairs, int E, int blk)
{
    __shared__ int cnt[256];
    __shared__ int basew[256];
    cnt[threadIdx.x] = 0;
    __syncthreads();
    const int i0 = blk * 4096 + threadIdx.x;
    int b[16], lofs[16], pk[16];
    #pragma unroll
    for (int j = 0; j < 16; ++j) {
        int i = i0 + j * 256;
        if (i < E) {
            int d = dst[i];
            b[j] = d >> 8;
            lofs[j] = atomicAdd(&cnt[b[j]], 1);
            pk[j] = src[i] | ((d & 255) << 24);      // src < 2^24
        } else b[j] = -1;
    }
    __syncthreads();
    int c = cnt[threadIdx.x];
    if (c) basew[threadIdx.x] = atomicAdd(&cntG[threadIdx.x], c);
    __syncthreads();
    #pragma unroll
    for (int j = 0; j < 16; ++j)
        if (b[j] >= 0) {
            int pos = basew[b[j]] + lofs[j];
            if (pos < CAP) pairs[(size_t)b[j] * CAP + pos] = pk[j];
        }
}

// fused: [0, 2*ebs4) scatter both sides | [.., +gU+gI) input projections
__global__ __launch_bounds__(256)
void scatter_proj_kernel(const int* __restrict__ iu_src, const int* __restrict__ iu_dst,
                         int* __restrict__ cntGU, int* __restrict__ pairsU,
                         const int* __restrict__ ui_src, const int* __restrict__ ui_dst,
                         int* __restrict__ cntGI, int* __restrict__ pairsI,
                         int E, int ebs4,
                         const float* __restrict__ x_u, const ushort* __restrict__ pPu,
                         const float* __restrict__ bp_u, ushort* __restrict__ hU,
                         int N_U, int gU,
                         const float* __restrict__ x_i, const ushort* __restrict__ pPi,
                         const float* __restrict__ bp_i, ushort* __restrict__ hI, int N_I)
{
    const int b = blockIdx.x;
    if (b < ebs4)
        bscatter_body(iu_src, iu_dst, cntGU, pairsU, E, b);
    else if (b < 2 * ebs4)
        bscatter_body(ui_src, ui_dst, cntGI, pairsI, E, b - ebs4);
    else if (b < 2 * ebs4 + gU)
        mfma_gemm_body<128, 8, false, true, true, true>(x_u, pPu, bp_u, hU, N_U,
                                                        b - 2 * ebs4);
    else
        mfma_gemm_body<64, 8, false, true, true, true>(x_i, pPi, bp_i, hI, N_I,
                                                       b - 2 * ebs4 - gU);
}

// ---------------- bucket fill body: window -> per-node lists + rowBE --------
__device__ __forceinline__ void bfill_body(
    const int* __restrict__ cntG, int2* __restrict__ rowBE,
    int* __restrict__ lists, const int* __restrict__ pairs, int N, int lb)
{
    __shared__ int stage[CAP];
    __shared__ int cnt[256];
    __shared__ int buf[256];
    __shared__ int cur[256];
    const int t = threadIdx.x;
    const int base = lb * CAP;
    const int n = min(cntG[lb], CAP);
    cnt[t] = 0;
    __syncthreads();
    for (int k = t; k < n; k += 256) {
        int v = pairs[(size_t)base + k];
        stage[k] = v;
        atomicAdd(&cnt[(v >> 24) & 255], 1);
    }
    __syncthreads();
    int val = cnt[t];
    buf[t] = val;
    __syncthreads();
    #pragma unroll
    for (int off = 1; off < 256; off <<= 1) {
        int x = (t >= off) ? buf[t - off] : 0;
        __syncthreads();
        buf[t] += x;
        __syncthreads();
    }
    int excl = buf[t] - val;
    int node = lb * 256 + t;
    if (node < N) rowBE[node] = make_int2(base + excl, base + excl + val);
    cur[t] = excl;
    __syncthreads();
    for (int k = t; k < n; k += 256) {
        int v = stage[k];
        int dl = (v >> 24) & 255;
        int pos = base + atomicAdd(&cur[dl], 1);
        lists[pos] = v & 0xFFFFFF;
    }
}

// fused: [0, nbkU+nbkI) bucket fill | [.., +gU+gI) layer-0 split GEMM
__global__ __launch_bounds__(256)
void fill_gemm_kernel(const int* __restrict__ cntGU, int2* __restrict__ rowBEU,
                      int* __restrict__ listsU, const int* __restrict__ pairsU,
                      int N_U, int nbkU,
                      const int* __restrict__ cntGI, int2* __restrict__ rowBEI,
                      int* __restrict__ listsI, const int* __restrict__ pairsI,
                      int N_I, int nbkI,
                      const ushort* __restrict__ hU, const ushort* __restrict__ Wp,
                      ushort* __restrict__ Ya_u, ushort* __restrict__ Yb_u, int gU,
                      const ushort* __restrict__ hI,
                      ushort* __restrict__ Ya_i, ushort* __restrict__ Yb_i)
{
    const int b = blockIdx.x;
    if (b < nbkU)
        bfill_body(cntGU, rowBEU, listsU, pairsU, N_U, b);
    else if (b < nbkU + nbkI)
        bfill_body(cntGI, rowBEI, listsI, pairsI, N_I, b - nbkU);
    else if (b < nbkU + nbkI + gU)
        mfma_gemm_split_body(hU, Wp, Ya_u, Yb_u, N_U, b - nbkU - nbkI);
    else
        mfma_gemm_split_body(hI, Wp, Ya_i, Yb_i, N_I, b - nbkU - nbkI - gU);
}

// ---------------- fused gather + SAGE update -----------------
// 1 wave per node; 4 groups x 16 lanes; lane owns 8 cols (uint4 = 16 B);
// 8 edges in flight. Combine: shfl_xor 16, 32. Tables dense [N,128].
// Update (folded): o = relu((s*sc + y) * S2[c] + B2[c]).
template<bool AGG>
__device__ __forceinline__ void gather_body(
    const ushort* __restrict__ Ysrc, const ushort* __restrict__ Ydst,
    ushort* __restrict__ hB,
    const int2* __restrict__ rowBE, const int* __restrict__ lists,
    const float* __restrict__ S2, const float* __restrict__ B2,
    int N, int blk)
{
    const int node = blk * 4 + (threadIdx.x >> 6);
    if (node >= N) return;
    const int lane = threadIdx.x & 63;
    const int grp  = lane >> 4;
    const int c8   = (lane & 15) * 8;

    const int2 be = rowBE[node];
    const int beg = be.x, end = be.y;

    float s[8] = {0.f, 0.f, 0.f, 0.f, 0.f, 0.f, 0.f, 0.f};
    int e = beg + grp;
    for (; e + 4 < end; e += 8) {                 // 8 edges in flight per wave
        int s0 = lists[e], s1 = lists[e + 4];
        uint4 v0 = *(const uint4*)&Ysrc[(size_t)s0 * H + c8];
        uint4 v1 = *(const uint4*)&Ysrc[(size_t)s1 * H + c8];
        acc2(s[0], s[1], v0.x); acc2(s[0], s[1], v1.x);
        acc2(s[2], s[3], v0.y); acc2(s[2], s[3], v1.y);
        acc2(s[4], s[5], v0.z); acc2(s[4], s[5], v1.z);
        acc2(s[6], s[7], v0.w); acc2(s[6], s[7], v1.w);
    }
    if (e < end) {
        int s0 = lists[e];
        uint4 v0 = *(const uint4*)&Ysrc[(size_t)s0 * H + c8];
        acc2(s[0], s[1], v0.x);
        acc2(s[2], s[3], v0.y);
        acc2(s[4], s[5], v0.z);
        acc2(s[6], s[7], v0.w);
    }
    #pragma unroll
    for (int j = 0; j < 8; ++j) {
        s[j] += __shfl_xor(s[j], 16, 64);
        s[j] += __shfl_xor(s[j], 32, 64);
    }
    if (grp != 0) return;                          // lanes 0-15 finish the node
    const int deg = end - beg;
    const float sc = (deg > 0) ? 1.0f / (float)deg : 0.f;

    if constexpr (AGG) {
        ushort hb[8];
        #pragma unroll
        for (int j = 0; j < 8; ++j) hb[j] = f2b(s[j] * sc);
        *(uint4*)&hB[(size_t)node * H + c8] = *(uint4*)hb;
        return;
    } else {
        // odd accumulators carry an extra 2^16 scale? No: s_odd summed values
        // w & 0xFFFF0000 ARE the bf16 floats directly (no shift) — exact.
        uint4 yv = *(const uint4*)&Ydst[(size_t)node * H + c8];
        float y[8] = { b2f((ushort)yv.x), b2f((ushort)(yv.x >> 16)),
                       b2f((ushort)yv.y), b2f((ushort)(yv.y >> 16)),
                       b2f((ushort)yv.z), b2f((ushort)(yv.z >> 16)),
                       b2f((ushort)yv.w), b2f((ushort)(yv.w >> 16)) };
        ushort hb[8];
        #pragma unroll
        for (int j = 0; j < 8; ++j) {
            float u = fmaf(fmaf(s[j], sc, y[j]), S2[c8 + j], B2[c8 + j]);
            hb[j] = f2b(fmaxf(u, 0.f));
        }
        *(uint4*)&hB[(size_t)node * H + c8] = *(uint4*)hb;
    }
}

// layer-0 I-side gather (runs first; produces hI)
__global__ __launch_bounds__(256)
void gather2I_kernel(const ushort* __restrict__ Ya_u, const ushort* __restrict__ Yb_i,
                     ushort* __restrict__ hI,
                     const int2* __restrict__ beI, const int* __restrict__ liI,
                     const float* __restrict__ S2, const float* __restrict__ B2,
                     int N_I)
{
    gather_body<false>(Ya_u, Yb_i, hI, beI, liI, S2, B2, N_I, blockIdx.x);
}

// layer-0 U-side gather fused with layer-1 I GEMM (Yi8 = hI @ Wl1 -> Yb_i)
__global__ __launch_bounds__(256)
void gatherU_gemmI_kernel(const ushort* __restrict__ Ya_i, const ushort* __restrict__ Yb_u,
                          ushort* __restrict__ hU,
                          const int2* __restrict__ beU, const int* __restrict__ liU,
                          const float* __restrict__ S2, const float* __restrict__ B2,
                          int N_U, int aU,
                          const ushort* __restrict__ hI, const ushort* __restrict__ pL1a,
                          ushort* __restrict__ Yi8, int N_I)
{
    if ((int)blockIdx.x < aU)
        gather_body<false>(Ya_i, Yb_u, hU, beU, liU, S2, B2, N_U, blockIdx.x);
    else
        mfma_gemm_body<128, 8, true, false, false, true>(hI, pL1a, nullptr, Yi8, N_I,
                                                         blockIdx.x - aU);
}

// layer-1 gather: U side only, agg-only output (bf16 mean of Yi8 rows)
__global__ __launch_bounds__(256)
void gather1agg_kernel(const ushort* __restrict__ Yi8, ushort* __restrict__ aggU,
                       const int2* __restrict__ beU, const int* __restrict__ liU,
                       int N_U)
{
    gather_body<true>(Yi8, nullptr, aggU, beU, liU, nullptr, nullptr, N_U, blockIdx.x);
}

// ---------------- tail: {hU@(Wr1+I) + Agg -> foldedBN -> relu} -> out1,
//                  then relu-tile @ Wh + bh -> out0 --------------------------
__global__ __launch_bounds__(256)
void tail_kernel(const ushort* __restrict__ hU, const ushort* __restrict__ pWr1,
                 const ushort* __restrict__ aggU,
                 const float* __restrict__ S2, const float* __restrict__ B2,
                 const ushort* __restrict__ pH, const float* __restrict__ bh,
                 float* __restrict__ out0, float* __restrict__ out1, int M)
{
    constexpr int LDT = H + 8;            // padded ushort stride (bank shift 4)
    __shared__ ushort T[64 * LDT];        // relu output tile (A for head MFMA)
    __shared__ ushort AG[64 * LDT];       // staged agg tile
    const int wave  = threadIdx.x >> 6;
    const int lane  = threadIdx.x & 63;
    const int row0g = blockIdx.x * 64;
    const int row0  = row0g + wave * 16;

    // stage Agg tile (64 x 128 bf16) coalesced
    #pragma unroll
    for (int i = 0; i < 4; ++i) {
        int idx = i * 256 + threadIdx.x;          // uint4 index; 1024 total
        int r = idx >> 4;
        int c = (idx & 15) * 8;
        int gr = row0g + r; if (gr >= M) gr = M - 1;
        uint4 v = *(const uint4*)&aggU[(size_t)gr * H + c];
        *(uint4*)&AG[r * LDT + c] = v;
    }

    // MFMA 1: hU @ (Wr1 + I), NCT=8
    int ar = row0 + (lane & 15); if (ar >= M) ar = M - 1;
    const ushort* arow = hU + (size_t)ar * H + (lane >> 4) * 8;
    const bf16x8* W8 = (const bf16x8*)pWr1;
    f32x4 acc[8];
    #pragma unroll
    for (int t = 0; t < 8; ++t) acc[t] = (f32x4){0.f, 0.f, 0.f, 0.f};
    #pragma unroll
    for (int s = 0; s < 4; ++s) {
        bf16x8 a = *(const bf16x8*)(arow + s * 32);
        #pragma unroll
        for (int t = 0; t < 8; ++t) {
            bf16x8 b = W8[(size_t)(s * 8 + t) * 64 + lane];
            acc[t] = __builtin_amdgcn_mfma_f32_16x16x32_bf16(a, b, acc[t], 0, 0, 0);
        }
    }
    __syncthreads();                      // AG staged

    const int cg = lane & 15;
    const int rg = (lane >> 4) * 4;
    #pragma unroll
    for (int t = 0; t < 8; ++t) {
        int col = t * 16 + cg;
        float s2 = S2[col], b2 = B2[col];
        #pragma unroll
        for (int r = 0; r < 4; ++r) {
            int lr = wave * 16 + rg + r;
            int grow = row0 + rg + r;
            float u = fmaf(acc[t][r] + b2f(AG[lr * LDT + col]), s2, b2);
            float o = fmaxf(u, 0.f);
            T[lr * LDT + col] = f2b(o);
            if (grow < M) out1[(size_t)grow * H + col] = o;
        }
    }
    __syncthreads();                      // T complete

    // MFMA 2: T @ Wh (NCT=2)
    const bf16x8* H8 = (const bf16x8*)pH;
    f32x4 acc2v[2];
    acc2v[0] = (f32x4){0.f, 0.f, 0.f, 0.f};
    acc2v[1] = (f32x4){0.f, 0.f, 0.f, 0.f};
    const ushort* trow = &T[(wave * 16 + (lane & 15)) * LDT + (lane >> 4) * 8];
    #pragma unroll
    for (int s = 0; s < 4; ++s) {
        bf16x8 a = *(const bf16x8*)(trow + s * 32);
        #pragma unroll
        for (int t = 0; t < 2; ++t) {
            bf16x8 b = H8[(size_t)(s * 2 + t) * 64 + lane];
            acc2v[t] = __builtin_amdgcn_mfma_f32_16x16x32_bf16(a, b, acc2v[t], 0, 0, 0);
        }
    }
    #pragma unroll
    for (int t = 0; t < 2; ++t) {
        int col = t * 16 + cg;
        float bb = bh[col];
        #pragma unroll
        for (int r = 0; r < 4; ++r) {
            int grow = row0 + rg + r;
            if (grow < M) out0[(size_t)grow * 32 + col] = acc2v[t][r] + bb;
        }
    }
}

extern "C" void kernel_launch(void* const* d_in, const int* in_sizes, int n_in,
                              void* d_out, int out_size, void* d_ws, size_t ws_size,
                              hipStream_t stream)
{
    const float* x_u   = (const float*)d_in[0];
    const float* x_i   = (const float*)d_in[1];
    const int*   iu_src = (const int*)d_in[2];
    const int*   iu_dst = (const int*)d_in[3];
    const int*   ui_src = (const int*)d_in[4];
    const int*   ui_dst = (const int*)d_in[5];
    const float* Wp_u  = (const float*)d_in[6];
    const float* bp_u  = (const float*)d_in[7];
    const float* Wp_i  = (const float*)d_in[8];
    const float* bp_i  = (const float*)d_in[9];
    const float* Wl    = (const float*)d_in[10];
    const float* bl    = (const float*)d_in[11];
    const float* Wr    = (const float*)d_in[12];
    const float* gamma = (const float*)d_in[13];
    const float* beta  = (const float*)d_in[14];
    const float* mean  = (const float*)d_in[15];
    const float* var   = (const float*)d_in[16];
    const float* Wh    = (const float*)d_in[17];
    const float* bh    = (const float*)d_in[18];

    const int N_U = in_sizes[0] / 128;      // 50000
    const int N_I = in_sizes[1] / 64;       // 30000
    const int E   = in_sizes[2];            // 500000
    const int OUT = 32;

    float* out  = (float*)d_out;
    float* out1 = out + (size_t)N_U * OUT;

    const int nbkU = (N_U + 255) / 256;     // buckets
    const int nbkI = (N_I + 255) / 256;

    // workspace layout (all Y tables dense [N,128] bf16)
    ushort* hU   = (ushort*)d_ws;                     // [N_U,128]
    ushort* hI   = hU + (size_t)N_U * H;              // [N_I,128]
    ushort* Ya_u = hI + (size_t)N_I * H;              // [N_U,128] h_u@Wl0 (gathered by I)
    ushort* Yb_u = Ya_u + (size_t)N_U * H;            // [N_U,128] h_u@(Wr0+I) / aggU (l1)
    ushort* Ya_i = Yb_u + (size_t)N_U * H;            // [N_I,128] h_i@Wl0 (gathered by U)
    ushort* Yb_i = Ya_i + (size_t)N_I * H;            // [N_I,128] h_i@(Wr0+I) / Yi8 (l1)
    int*    ip   = (int*)(((uintptr_t)(Yb_i + (size_t)N_I * H) + 15) & ~(uintptr_t)15);
    int2* rowBEU = (int2*)ip;        ip += 2 * N_U;
    int2* rowBEI = (int2*)ip;        ip += 2 * N_I;
    int* listsU  = ip;               ip += nbkU * CAP;
    int* listsI  = ip;               ip += nbkI * CAP;
    int* pairsU  = ip;               ip += nbkU * CAP;
    int* pairsI  = ip;               ip += nbkI * CAP;
    int* cntGU   = ip;               ip += 256;
    int* cntGI   = ip;               ip += 256;
    float* bnS   = (float*)ip;       ip += 384;
    float* bnB   = (float*)ip;       ip += 384;
    // packed weights (bf16), 16B-aligned
    ushort* up   = (ushort*)(((uintptr_t)ip + 15) & ~(uintptr_t)15);
    ushort* pPu  = up;               up += 4 * 8  * 64 * 8;   // K=128, NCT=8
    ushort* pPi  = up;               up += 2 * 8  * 64 * 8;   // K=64,  NCT=8
    ushort* pL0  = up;               up += 4 * 16 * 64 * 8;   // [Wl0 | Wr0+I]
    ushort* pL1a = up;               up += 4 * 8  * 64 * 8;   // Wl1
    ushort* pL1b = up;               up += 4 * 8  * 64 * 8;   // Wr1 + I
    ushort* pH   = up;               up += 4 * 2  * 64 * 8;   // Wh

    const int ebs4 = (E + 4095) / 4096;     // scatter blocks per side
    const int gU   = (N_U + 63) / 64;       // gemm blocks
    const int gI   = (N_I + 63) / 64;
    const int aU   = (N_U + 3) / 4;         // gather blocks
    const int aI   = (N_I + 3) / 4;

    // ---- pack weights + zero counters + folded BN tables ----
    pack_all_kernel<<<50, 256, 0, stream>>>(
        Wp_u, Wp_i, Wl, Wr, Wh, bl, gamma, beta, mean, var,
        pPu, pPi, pL0, pL1a, pL1b, pH, cntGU, bnS, bnB);

    // ---- fused: bucket-scatter (both sides) || input projections ----
    scatter_proj_kernel<<<2 * ebs4 + gU + gI, 256, 0, stream>>>(
        iu_src, iu_dst, cntGU, pairsU,
        ui_src, ui_dst, cntGI, pairsI, E, ebs4,
        x_u, pPu, bp_u, hU, N_U, gU,
        x_i, pPi, bp_i, hI, N_I);

    // ---- fused: bucket-fill (both sides) || layer-0 split GEMM ----
    fill_gemm_kernel<<<nbkU + nbkI + gU + gI, 256, 0, stream>>>(
        cntGU, rowBEU, listsU, pairsU, N_U, nbkU,
        cntGI, rowBEI, listsI, pairsI, N_I, nbkI,
        hU, pL0, Ya_u, Yb_u, gU, hI, Ya_i, Yb_i);

    // ---- layer 0: I-side gather (produces hI) ----
    gather2I_kernel<<<aI, 256, 0, stream>>>(
        Ya_u, Yb_i, hI, rowBEI, listsI, bnS + 128, bnB + 128, N_I);

    // ---- layer 0 U-gather || layer-1 I GEMM (Yi8 = hI@Wl1 -> Yb_i) ----
    gatherU_gemmI_kernel<<<aU + gI, 256, 0, stream>>>(
        Ya_i, Yb_u, hU, rowBEU, listsU, bnS, bnB, N_U, aU,
        hI, pL1a, Yb_i, N_I);

    // ---- layer 1: U-side agg only -> bf16 aggU (reuses Yb_u) ----
    gather1agg_kernel<<<aU, 256, 0, stream>>>(Yb_i, Yb_u, rowBEU, listsU, N_U);

    // ---- tail: hU@(Wr1+I) + Agg -> foldedBN -> relu -> out1; @Wh+bh -> out0 ----
    tail_kernel<<<gU, 256, 0, stream>>>(
        hU, pL1b, Yb_u, bnS + 256, bnB + 256, pH, bh, out, out1, N_U);
}

// Round 17
// 150.394 us; speedup vs baseline: 1.0835x; 1.0806x over previous
//
#include <hip/hip_runtime.h>

constexpr int H = 128;
constexpr int CAP = 8192;   // bucket window capacity (mean fill <= 4.3k, sigma ~65)

typedef short bf16x8 __attribute__((ext_vector_type(8)));
typedef float f32x4  __attribute__((ext_vector_type(4)));

__device__ __forceinline__ ushort f2b(float f) {
    uint u = __float_as_uint(f);
    u += 0x7fff + ((u >> 16) & 1);      // round-to-nearest-even
    return (ushort)(u >> 16);
}
__device__ __forceinline__ float b2f(ushort b) {
    return __uint_as_float((uint)b << 16);
}

// accumulate 2 bf16 (packed in w) into even/odd f32 accumulators.
// NOTE: fdot2_f32_bf16 builtin mis-executes on gfx950 (R15 fail) — plain path.
__device__ __forceinline__ void acc2(float& se, float& so, uint w) {
    se += __uint_as_float(w << 16);
    so += __uint_as_float(w & 0xFFFF0000u);
}

// ---------------- W pack: frag[s][t0+t][lane][j] = W'[s*32+8*(l/16)+j][t*16+l%16]
__device__ __forceinline__ void pack_one(const float* __restrict__ W, int ldw,
                                         int t0, int nct, int nctTot,
                                         ushort* __restrict__ dst, int fgl, int l,
                                         float addI)
{
    int t = fgl % nct, s = fgl / nct;
    int col = t * 16 + (l & 15);
    int kb  = s * 32 + (l >> 4) * 8;
    ushort o[8];
    #pragma unroll
    for (int j = 0; j < 8; ++j) {
        float v = W[(size_t)(kb + j) * ldw + col];
        if (kb + j == col) v += addI;
        o[j] = f2b(v);
    }
    ushort* d = dst + ((size_t)(s * nctTot + t0 + t) * 64 + l) * 8;
    *(uint4*)d = *(uint4*)o;
}

// all weights + cntG zero + folded BN/bias tables:
//   bnS[t*128+c], bnB[t*128+c]; t=0: layer0 U (BN), t=1: layer0 I (no BN),
//   t=2: layer1 U (BN). update: o = relu((s*sc + y) * S2 + B2).
__global__ __launch_bounds__(256)
void pack_all_kernel(const float* __restrict__ Wp_u, const float* __restrict__ Wp_i,
                     const float* __restrict__ Wl, const float* __restrict__ Wr,
                     const float* __restrict__ Wh,
                     const float* __restrict__ bl, const float* __restrict__ gamma,
                     const float* __restrict__ beta, const float* __restrict__ mean,
                     const float* __restrict__ var,
                     ushort* __restrict__ pPu, ushort* __restrict__ pPi,
                     ushort* __restrict__ pL0, ushort* __restrict__ pL1a,
                     ushort* __restrict__ pL1b, ushort* __restrict__ pH,
                     int* __restrict__ cntG, float* __restrict__ bnS,
                     float* __restrict__ bnB)
{
    int f = blockIdx.x * 256 + threadIdx.x;
    int fg = f >> 6, l = f & 63;
    if (fg < 32)       pack_one(Wp_u,          128, 0, 8, 8,  pPu,  fg,       l, 0.f);
    else if (fg < 48)  pack_one(Wp_i,          128, 0, 8, 8,  pPi,  fg - 32,  l, 0.f);
    else if (fg < 80)  pack_one(Wl,            128, 0, 8, 16, pL0,  fg - 48,  l, 0.f);
    else if (fg < 112) pack_one(Wr,            128, 8, 8, 16, pL0,  fg - 80,  l, 1.f);
    else if (fg < 144) pack_one(Wl + H * H,    128, 0, 8, 8,  pL1a, fg - 112, l, 0.f);
    else if (fg < 176) pack_one(Wr + H * H,    128, 0, 8, 8,  pL1b, fg - 144, l, 1.f);
    else if (fg < 184) pack_one(Wh,             32, 0, 2, 2,  pH,   fg - 176, l, 0.f);
    else {
        int k = f - 184 * 64;
        if (k < 512) cntG[k] = 0;
        else if (k < 512 + 384) {
            int idx = k - 512;
            int t = idx >> 7, c = idx & 127;
            if (t == 1) {
                bnS[128 + c] = 0.5f;
                bnB[128 + c] = 0.5f * bl[c];
            } else {
                int o = (t == 0) ? 0 : H;     // layer offset
                float S = rsqrtf(var[o + c] + 1e-5f) * gamma[o + c];
                bnS[t * 128 + c] = 0.5f * S;
                bnB[t * 128 + c] = beta[o + c] - mean[o + c] * S + 0.5f * bl[o + c] * S;
            }
        }
    }
}

// ---------------- MFMA GEMM body (A fp32 or bf16; C fp32 or bf16) ----------
template<int K, int NCT, bool ABF16, bool BIAS, bool RELU, bool OBF16>
__device__ __forceinline__ void mfma_gemm_body(
    const void* __restrict__ Av, const ushort* __restrict__ Wp,
    const float* __restrict__ bias, void* __restrict__ Cv, int M, int blk)
{
    constexpr int S   = K / 32;
    constexpr int LDC = NCT * 16;
    const int wave = threadIdx.x >> 6;
    const int lane = threadIdx.x & 63;
    const int row0 = blk * 64 + wave * 16;

    int ar = row0 + (lane & 15);
    if (ar >= M) ar = M - 1;                      // clamp loads; stores guarded
    const bf16x8* W8 = (const bf16x8*)Wp;

    f32x4 acc[NCT];
    #pragma unroll
    for (int t = 0; t < NCT; ++t) acc[t] = (f32x4){0.f, 0.f, 0.f, 0.f};

    #pragma unroll
    for (int s = 0; s < S; ++s) {
        bf16x8 a;
        if constexpr (ABF16) {
            const ushort* arow = (const ushort*)Av + (size_t)ar * K + (lane >> 4) * 8;
            a = *(const bf16x8*)(arow + s * 32);
        } else {
            const float* arow = (const float*)Av + (size_t)ar * K + (lane >> 4) * 8;
            float4 f0 = *(const float4*)(arow + s * 32);
            float4 f1 = *(const float4*)(arow + s * 32 + 4);
            a[0] = (short)f2b(f0.x); a[1] = (short)f2b(f0.y);
            a[2] = (short)f2b(f0.z); a[3] = (short)f2b(f0.w);
            a[4] = (short)f2b(f1.x); a[5] = (short)f2b(f1.y);
            a[6] = (short)f2b(f1.z); a[7] = (short)f2b(f1.w);
        }
        #pragma unroll
        for (int t = 0; t < NCT; ++t) {
            bf16x8 b = W8[(size_t)(s * NCT + t) * 64 + lane];
            acc[t] = __builtin_amdgcn_mfma_f32_16x16x32_bf16(a, b, acc[t], 0, 0, 0);
        }
    }

    const int cg = lane & 15;
    const int rg = (lane >> 4) * 4;
    #pragma unroll
    for (int t = 0; t < NCT; ++t) {
        int col = t * 16 + cg;
        float bb = 0.f;
        if constexpr (BIAS) bb = bias[col];
        #pragma unroll
        for (int r = 0; r < 4; ++r) {
            int row = row0 + rg + r;
            if (row < M) {
                float v = acc[t][r] + bb;
                if constexpr (RELU) v = fmaxf(v, 0.f);
                if constexpr (OBF16)
                    ((ushort*)Cv)[(size_t)row * LDC + col] = f2b(v);
                else
                    ((float*)Cv)[(size_t)row * LDC + col] = v;
            }
        }
    }
}

// ---- layer-0 GEMM with SPLIT outputs: Ya = A@Wl (dense), Yb = A@(Wr+I) -----
__device__ __forceinline__ void mfma_gemm_split_body(
    const ushort* __restrict__ A, const ushort* __restrict__ Wp,
    ushort* __restrict__ Ca, ushort* __restrict__ Cb, int M, int blk)
{
    const int wave = threadIdx.x >> 6;
    const int lane = threadIdx.x & 63;
    const int row0 = blk * 64 + wave * 16;

    int ar = row0 + (lane & 15);
    if (ar >= M) ar = M - 1;
    const ushort* arow = A + (size_t)ar * H + (lane >> 4) * 8;
    const bf16x8* W8 = (const bf16x8*)Wp;

    f32x4 acc[16];
    #pragma unroll
    for (int t = 0; t < 16; ++t) acc[t] = (f32x4){0.f, 0.f, 0.f, 0.f};

    #pragma unroll
    for (int s = 0; s < 4; ++s) {
        bf16x8 a = *(const bf16x8*)(arow + s * 32);
        #pragma unroll
        for (int t = 0; t < 16; ++t) {
            bf16x8 b = W8[(size_t)(s * 16 + t) * 64 + lane];
            acc[t] = __builtin_amdgcn_mfma_f32_16x16x32_bf16(a, b, acc[t], 0, 0, 0);
        }
    }

    const int cg = lane & 15;
    const int rg = (lane >> 4) * 4;
    #pragma unroll
    for (int t = 0; t < 16; ++t) {
        ushort* C = (t < 8) ? Ca : Cb;
        int col = (t & 7) * 16 + cg;
        #pragma unroll
        for (int r = 0; r < 4; ++r) {
            int row = row0 + rg + r;
            if (row < M) C[(size_t)row * H + col] = f2b(acc[t][r]);
        }
    }
}

// ------- bucket scatter body (4096 edges/block, LDS counting-sort) ----------
// Sorts the block's edges by bucket in LDS, reserves each bucket's global
// range with ONE atomic, then writes each bucket run CONTIGUOUSLY.
__device__ __forceinline__ void bscatter_body(
    const int* __restrict__ src, const int* __restrict__ dst,
    int* __restrict__ cntG, int* __restrict__ pairs, int E, int blk)
{
    __shared__ int pkL[4096];
    __shared__ unsigned char bkL[4096];
    __shared__ int cnt[256];
    __shared__ int buf[256];
    __shared__ int lbase[256];
    __shared__ int gbase[256];
    const int t = threadIdx.x;
    cnt[t] = 0;
    __syncthreads();
    const int i0 = blk * 4096 + t;
    const int n  = min(4096, E - blk * 4096);
    int b[16], lofs[16], pk[16];
    #pragma unroll
    for (int j = 0; j < 16; ++j) {
        int i = i0 + j * 256;
        if (i < E) {
            int d = dst[i];
            b[j] = d >> 8;
            lofs[j] = atomicAdd(&cnt[b[j]], 1);
            pk[j] = src[i] | ((d & 255) << 24);      // src < 2^24
        } else b[j] = -1;
    }
    __syncthreads();
    int c = cnt[t];
    buf[t] = c;
    __syncthreads();
    #pragma unroll
    for (int off = 1; off < 256; off <<= 1) {
        int x = (t >= off) ? buf[t - off] : 0;
        __syncthreads();
        buf[t] += x;
        __syncthreads();
    }
    lbase[t] = buf[t] - c;
    if (c) gbase[t] = atomicAdd(&cntG[t], c);
    __syncthreads();
    #pragma unroll
    for (int j = 0; j < 16; ++j)
        if (b[j] >= 0) {
            int p = lbase[b[j]] + lofs[j];
            pkL[p] = pk[j];
            bkL[p] = (unsigned char)b[j];
        }
    __syncthreads();
    for (int k = t; k < n; k += 256) {
        int bb  = bkL[k];
        int pos = gbase[bb] + (k - lbase[bb]);
        if (pos < CAP) pairs[(size_t)bb * CAP + pos] = pkL[k];
    }
}

// fused: [0, 2*ebs4) scatter both sides | [.., +gU+gI) input projections
__global__ __launch_bounds__(256)
void scatter_proj_kernel(const int* __restrict__ iu_src, const int* __restrict__ iu_dst,
                         int* __restrict__ cntGU, int* __restrict__ pairsU,
                         const int* __restrict__ ui_src, const int* __restrict__ ui_dst,
                         int* __restrict__ cntGI, int* __restrict__ pairsI,
                         int E, int ebs4,
                         const float* __restrict__ x_u, const ushort* __restrict__ pPu,
                         const float* __restrict__ bp_u, ushort* __restrict__ hU,
                         int N_U, int gU,
                         const float* __restrict__ x_i, const ushort* __restrict__ pPi,
                         const float* __restrict__ bp_i, ushort* __restrict__ hI, int N_I)
{
    const int b = blockIdx.x;
    if (b < ebs4)
        bscatter_body(iu_src, iu_dst, cntGU, pairsU, E, b);
    else if (b < 2 * ebs4)
        bscatter_body(ui_src, ui_dst, cntGI, pairsI, E, b - ebs4);
    else if (b < 2 * ebs4 + gU)
        mfma_gemm_body<128, 8, false, true, true, true>(x_u, pPu, bp_u, hU, N_U,
                                                        b - 2 * ebs4);
    else
        mfma_gemm_body<64, 8, false, true, true, true>(x_i, pPi, bp_i, hI, N_I,
                                                       b - 2 * ebs4 - gU);
}

// ---------------- bucket fill body: window -> per-node lists + rowBE --------
__device__ __forceinline__ void bfill_body(
    const int* __restrict__ cntG, int2* __restrict__ rowBE,
    int* __restrict__ lists, const int* __restrict__ pairs, int N, int lb)
{
    __shared__ int stage[CAP];
    __shared__ int cnt[256];
    __shared__ int buf[256];
    __shared__ int cur[256];
    const int t = threadIdx.x;
    const int base = lb * CAP;
    const int n = min(cntG[lb], CAP);
    cnt[t] = 0;
    __syncthreads();
    for (int k = t; k < n; k += 256) {
        int v = pairs[(size_t)base + k];
        stage[k] = v;
        atomicAdd(&cnt[(v >> 24) & 255], 1);
    }
    __syncthreads();
    int val = cnt[t];
    buf[t] = val;
    __syncthreads();
    #pragma unroll
    for (int off = 1; off < 256; off <<= 1) {
        int x = (t >= off) ? buf[t - off] : 0;
        __syncthreads();
        buf[t] += x;
        __syncthreads();
    }
    int excl = buf[t] - val;
    int node = lb * 256 + t;
    if (node < N) rowBE[node] = make_int2(base + excl, base + excl + val);
    cur[t] = excl;
    __syncthreads();
    for (int k = t; k < n; k += 256) {
        int v = stage[k];
        int dl = (v >> 24) & 255;
        int pos = base + atomicAdd(&cur[dl], 1);
        lists[pos] = v & 0xFFFFFF;
    }
}

// fused: [0, nbkU+nbkI) bucket fill | [.., +gU+gI) layer-0 split GEMM
__global__ __launch_bounds__(256)
void fill_gemm_kernel(const int* __restrict__ cntGU, int2* __restrict__ rowBEU,
                      int* __restrict__ listsU, const int* __restrict__ pairsU,
                      int N_U, int nbkU,
                      const int* __restrict__ cntGI, int2* __restrict__ rowBEI,
                      int* __restrict__ listsI, const int* __restrict__ pairsI,
                      int N_I, int nbkI,
                      const ushort* __restrict__ hU, const ushort* __restrict__ Wp,
                      ushort* __restrict__ Ya_u, ushort* __restrict__ Yb_u, int gU,
                      const ushort* __restrict__ hI,
                      ushort* __restrict__ Ya_i, ushort* __restrict__ Yb_i)
{
    const int b = blockIdx.x;
    if (b < nbkU)
        bfill_body(cntGU, rowBEU, listsU, pairsU, N_U, b);
    else if (b < nbkU + nbkI)
        bfill_body(cntGI, rowBEI, listsI, pairsI, N_I, b - nbkU);
    else if (b < nbkU + nbkI + gU)
        mfma_gemm_split_body(hU, Wp, Ya_u, Yb_u, N_U, b - nbkU - nbkI);
    else
        mfma_gemm_split_body(hI, Wp, Ya_i, Yb_i, N_I, b - nbkU - nbkI - gU);
}

// layer-1 I-side GEMM: Yi8 = hI @ Wl1 (the only live I-half)
__global__ __launch_bounds__(256)
void gemmI_kernel(const ushort* __restrict__ hI, const ushort* __restrict__ pA,
                  ushort* __restrict__ Yi8, int N_I)
{
    mfma_gemm_body<128, 8, true, false, false, true>(hI, pA, nullptr, Yi8, N_I,
                                                     blockIdx.x);
}

// ---------------- fused gather + SAGE update -----------------
// 1 wave per node; 4 groups x 16 lanes; lane owns 8 cols (uint4 = 16 B);
// 8 edges in flight. Combine: shfl_xor 16, 32. Tables dense [N,128].
// Update (folded): o = relu((s*sc + y) * S2[c] + B2[c]).
template<bool AGG>
__device__ __forceinline__ void gather_body(
    const ushort* __restrict__ Ysrc, const ushort* __restrict__ Ydst,
    ushort* __restrict__ hB,
    const int2* __restrict__ rowBE, const int* __restrict__ lists,
    const float* __restrict__ S2, const float* __restrict__ B2,
    int N, int blk)
{
    const int node = blk * 4 + (threadIdx.x >> 6);
    if (node >= N) return;
    const int lane = threadIdx.x & 63;
    const int grp  = lane >> 4;
    const int c8   = (lane & 15) * 8;

    const int2 be = rowBE[node];
    const int beg = be.x, end = be.y;

    float s[8] = {0.f, 0.f, 0.f, 0.f, 0.f, 0.f, 0.f, 0.f};
    int e = beg + grp;
    for (; e + 4 < end; e += 8) {                 // 8 edges in flight per wave
        int s0 = lists[e], s1 = lists[e + 4];
        uint4 v0 = *(const uint4*)&Ysrc[(size_t)s0 * H + c8];
        uint4 v1 = *(const uint4*)&Ysrc[(size_t)s1 * H + c8];
        acc2(s[0], s[1], v0.x); acc2(s[0], s[1], v1.x);
        acc2(s[2], s[3], v0.y); acc2(s[2], s[3], v1.y);
        acc2(s[4], s[5], v0.z); acc2(s[4], s[5], v1.z);
        acc2(s[6], s[7], v0.w); acc2(s[6], s[7], v1.w);
    }
    if (e < end) {
        int s0 = lists[e];
        uint4 v0 = *(const uint4*)&Ysrc[(size_t)s0 * H + c8];
        acc2(s[0], s[1], v0.x);
        acc2(s[2], s[3], v0.y);
        acc2(s[4], s[5], v0.z);
        acc2(s[6], s[7], v0.w);
    }
    #pragma unroll
    for (int j = 0; j < 8; ++j) {
        s[j] += __shfl_xor(s[j], 16, 64);
        s[j] += __shfl_xor(s[j], 32, 64);
    }
    if (grp != 0) return;                          // lanes 0-15 finish the node
    const int deg = end - beg;
    const float sc = (deg > 0) ? 1.0f / (float)deg : 0.f;

    if constexpr (AGG) {
        ushort hb[8];
        #pragma unroll
        for (int j = 0; j < 8; ++j) hb[j] = f2b(s[j] * sc);
        *(uint4*)&hB[(size_t)node * H + c8] = *(uint4*)hb;
        return;
    } else {
        uint4 yv = *(const uint4*)&Ydst[(size_t)node * H + c8];
        float y[8] = { b2f((ushort)yv.x), b2f((ushort)(yv.x >> 16)),
                       b2f((ushort)yv.y), b2f((ushort)(yv.y >> 16)),
                       b2f((ushort)yv.z), b2f((ushort)(yv.z >> 16)),
                       b2f((ushort)yv.w), b2f((ushort)(yv.w >> 16)) };
        ushort hb[8];
        #pragma unroll
        for (int j = 0; j < 8; ++j) {
            float u = fmaf(fmaf(s[j], sc, y[j]), S2[c8 + j], B2[c8 + j]);
            hb[j] = f2b(fmaxf(u, 0.f));
        }
        *(uint4*)&hB[(size_t)node * H + c8] = *(uint4*)hb;
    }
}

// layer-0 gather: both sides in ONE dispatch (cross-side overlap; R16 split
// was net-negative: fused-gemm VGPR cut gather occupancy)
__global__ __launch_bounds__(256)
void gather2_kernel(const ushort* __restrict__ Ya_i, const ushort* __restrict__ Yb_u,
                    ushort* __restrict__ hU,
                    const int2* __restrict__ beU, const int* __restrict__ liU,
                    const float* __restrict__ bnS, const float* __restrict__ bnB,
                    int N_U, int nbU,
                    const ushort* __restrict__ Ya_u, const ushort* __restrict__ Yb_i,
                    ushort* __restrict__ hI,
                    const int2* __restrict__ beI, const int* __restrict__ liI, int N_I)
{
    if ((int)blockIdx.x < nbU)
        gather_body<false>(Ya_i, Yb_u, hU, beU, liU, bnS, bnB, N_U, blockIdx.x);
    else
        gather_body<false>(Ya_u, Yb_i, hI, beI, liI, bnS + 128, bnB + 128, N_I,
                           blockIdx.x - nbU);
}

// layer-1 gather: U side only, agg-only output (bf16 mean of Yi8 rows)
__global__ __launch_bounds__(256)
void gather1agg_kernel(const ushort* __restrict__ Yi8, ushort* __restrict__ aggU,
                       const int2* __restrict__ beU, const int* __restrict__ liU,
                       int N_U)
{
    gather_body<true>(Yi8, nullptr, aggU, beU, liU, nullptr, nullptr, N_U, blockIdx.x);
}

// ---------------- tail: {hU@(Wr1+I) + Agg -> foldedBN -> relu} -> out1,
//                  then relu-tile @ Wh + bh -> out0 --------------------------
__global__ __launch_bounds__(256)
void tail_kernel(const ushort* __restrict__ hU, const ushort* __restrict__ pWr1,
                 const ushort* __restrict__ aggU,
                 const float* __restrict__ S2, const float* __restrict__ B2,
                 const ushort* __restrict__ pH, const float* __restrict__ bh,
                 float* __restrict__ out0, float* __restrict__ out1, int M)
{
    constexpr int LDT = H + 8;            // padded ushort stride (bank shift 4)
    __shared__ ushort T[64 * LDT];        // relu output tile (A for head MFMA)
    __shared__ ushort AG[64 * LDT];       // staged agg tile
    const int wave  = threadIdx.x >> 6;
    const int lane  = threadIdx.x & 63;
    const int row0g = blockIdx.x * 64;
    const int row0  = row0g + wave * 16;

    // stage Agg tile (64 x 128 bf16) coalesced
    #pragma unroll
    for (int i = 0; i < 4; ++i) {
        int idx = i * 256 + threadIdx.x;          // uint4 index; 1024 total
        int r = idx >> 4;
        int c = (idx & 15) * 8;
        int gr = row0g + r; if (gr >= M) gr = M - 1;
        uint4 v = *(const uint4*)&aggU[(size_t)gr * H + c];
        *(uint4*)&AG[r * LDT + c] = v;
    }

    // MFMA 1: hU @ (Wr1 + I), NCT=8
    int ar = row0 + (lane & 15); if (ar >= M) ar = M - 1;
    const ushort* arow = hU + (size_t)ar * H + (lane >> 4) * 8;
    const bf16x8* W8 = (const bf16x8*)pWr1;
    f32x4 acc[8];
    #pragma unroll
    for (int t = 0; t < 8; ++t) acc[t] = (f32x4){0.f, 0.f, 0.f, 0.f};
    #pragma unroll
    for (int s = 0; s < 4; ++s) {
        bf16x8 a = *(const bf16x8*)(arow + s * 32);
        #pragma unroll
        for (int t = 0; t < 8; ++t) {
            bf16x8 b = W8[(size_t)(s * 8 + t) * 64 + lane];
            acc[t] = __builtin_amdgcn_mfma_f32_16x16x32_bf16(a, b, acc[t], 0, 0, 0);
        }
    }
    __syncthreads();                      // AG staged

    const int cg = lane & 15;
    const int rg = (lane >> 4) * 4;
    #pragma unroll
    for (int t = 0; t < 8; ++t) {
        int col = t * 16 + cg;
        float s2 = S2[col], b2 = B2[col];
        #pragma unroll
        for (int r = 0; r < 4; ++r) {
            int lr = wave * 16 + rg + r;
            int grow = row0 + rg + r;
            float u = fmaf(acc[t][r] + b2f(AG[lr * LDT + col]), s2, b2);
            float o = fmaxf(u, 0.f);
            T[lr * LDT + col] = f2b(o);
            if (grow < M) out1[(size_t)grow * H + col] = o;
        }
    }
    __syncthreads();                      // T complete

    // MFMA 2: T @ Wh (NCT=2)
    const bf16x8* H8 = (const bf16x8*)pH;
    f32x4 acc2v[2];
    acc2v[0] = (f32x4){0.f, 0.f, 0.f, 0.f};
    acc2v[1] = (f32x4){0.f, 0.f, 0.f, 0.f};
    const ushort* trow = &T[(wave * 16 + (lane & 15)) * LDT + (lane >> 4) * 8];
    #pragma unroll
    for (int s = 0; s < 4; ++s) {
        bf16x8 a = *(const bf16x8*)(trow + s * 32);
        #pragma unroll
        for (int t = 0; t < 2; ++t) {
            bf16x8 b = H8[(size_t)(s * 2 + t) * 64 + lane];
            acc2v[t] = __builtin_amdgcn_mfma_f32_16x16x32_bf16(a, b, acc2v[t], 0, 0, 0);
        }
    }
    #pragma unroll
    for (int t = 0; t < 2; ++t) {
        int col = t * 16 + cg;
        float bb = bh[col];
        #pragma unroll
        for (int r = 0; r < 4; ++r) {
            int grow = row0 + rg + r;
            if (grow < M) out0[(size_t)grow * 32 + col] = acc2v[t][r] + bb;
        }
    }
}

extern "C" void kernel_launch(void* const* d_in, const int* in_sizes, int n_in,
                              void* d_out, int out_size, void* d_ws, size_t ws_size,
                              hipStream_t stream)
{
    const float* x_u   = (const float*)d_in[0];
    const float* x_i   = (const float*)d_in[1];
    const int*   iu_src = (const int*)d_in[2];
    const int*   iu_dst = (const int*)d_in[3];
    const int*   ui_src = (const int*)d_in[4];
    const int*   ui_dst = (const int*)d_in[5];
    const float* Wp_u  = (const float*)d_in[6];
    const float* bp_u  = (const float*)d_in[7];
    const float* Wp_i  = (const float*)d_in[8];
    const float* bp_i  = (const float*)d_in[9];
    const float* Wl    = (const float*)d_in[10];
    const float* bl    = (const float*)d_in[11];
    const float* Wr    = (const float*)d_in[12];
    const float* gamma = (const float*)d_in[13];
    const float* beta  = (const float*)d_in[14];
    const float* mean  = (const float*)d_in[15];
    const float* var   = (const float*)d_in[16];
    const float* Wh    = (const float*)d_in[17];
    const float* bh    = (const float*)d_in[18];

    const int N_U = in_sizes[0] / 128;      // 50000
    const int N_I = in_sizes[1] / 64;       // 30000
    const int E   = in_sizes[2];            // 500000
    const int OUT = 32;

    float* out  = (float*)d_out;
    float* out1 = out + (size_t)N_U * OUT;

    const int nbkU = (N_U + 255) / 256;     // buckets
    const int nbkI = (N_I + 255) / 256;

    // workspace layout (all Y tables dense [N,128] bf16)
    ushort* hU   = (ushort*)d_ws;                     // [N_U,128]
    ushort* hI   = hU + (size_t)N_U * H;              // [N_I,128]
    ushort* Ya_u = hI + (size_t)N_I * H;              // [N_U,128] h_u@Wl0 (gathered by I)
    ushort* Yb_u = Ya_u + (size_t)N_U * H;            // [N_U,128] h_u@(Wr0+I) / aggU (l1)
    ushort* Ya_i = Yb_u + (size_t)N_U * H;            // [N_I,128] h_i@Wl0 (gathered by U)
    ushort* Yb_i = Ya_i + (size_t)N_I * H;            // [N_I,128] h_i@(Wr0+I) / Yi8 (l1)
    int*    ip   = (int*)(((uintptr_t)(Yb_i + (size_t)N_I * H) + 15) & ~(uintptr_t)15);
    int2* rowBEU = (int2*)ip;        ip += 2 * N_U;
    int2* rowBEI = (int2*)ip;        ip += 2 * N_I;
    int* listsU  = ip;               ip += nbkU * CAP;
    int* listsI  = ip;               ip += nbkI * CAP;
    int* pairsU  = ip;               ip += nbkU * CAP;
    int* pairsI  = ip;               ip += nbkI * CAP;
    int* cntGU   = ip;               ip += 256;
    int* cntGI   = ip;               ip += 256;
    float* bnS   = (float*)ip;       ip += 384;
    float* bnB   = (float*)ip;       ip += 384;
    // packed weights (bf16), 16B-aligned
    ushort* up   = (ushort*)(((uintptr_t)ip + 15) & ~(uintptr_t)15);
    ushort* pPu  = up;               up += 4 * 8  * 64 * 8;   // K=128, NCT=8
    ushort* pPi  = up;               up += 2 * 8  * 64 * 8;   // K=64,  NCT=8
    ushort* pL0  = up;               up += 4 * 16 * 64 * 8;   // [Wl0 | Wr0+I]
    ushort* pL1a = up;               up += 4 * 8  * 64 * 8;   // Wl1
    ushort* pL1b = up;               up += 4 * 8  * 64 * 8;   // Wr1 + I
    ushort* pH   = up;               up += 4 * 2  * 64 * 8;   // Wh

    const int ebs4 = (E + 4095) / 4096;     // scatter blocks per side
    const int gU   = (N_U + 63) / 64;       // gemm blocks
    const int gI   = (N_I + 63) / 64;
    const int aU   = (N_U + 3) / 4;         // gather blocks
    const int aI   = (N_I + 3) / 4;

    // ---- pack weights + zero counters + folded BN tables ----
    pack_all_kernel<<<50, 256, 0, stream>>>(
        Wp_u, Wp_i, Wl, Wr, Wh, bl, gamma, beta, mean, var,
        pPu, pPi, pL0, pL1a, pL1b, pH, cntGU, bnS, bnB);

    // ---- fused: sorted bucket-scatter (both sides) || input projections ----
    scatter_proj_kernel<<<2 * ebs4 + gU + gI, 256, 0, stream>>>(
        iu_src, iu_dst, cntGU, pairsU,
        ui_src, ui_dst, cntGI, pairsI, E, ebs4,
        x_u, pPu, bp_u, hU, N_U, gU,
        x_i, pPi, bp_i, hI, N_I);

    // ---- fused: bucket-fill (both sides) || layer-0 split GEMM ----
    fill_gemm_kernel<<<nbkU + nbkI + gU + gI, 256, 0, stream>>>(
        cntGU, rowBEU, listsU, pairsU, N_U, nbkU,
        cntGI, rowBEI, listsI, pairsI, N_I, nbkI,
        hU, pL0, Ya_u, Yb_u, gU, hI, Ya_i, Yb_i);

    // ---- layer 0: gather both sides (one dispatch, folded BN) ----
    gather2_kernel<<<aU + aI, 256, 0, stream>>>(
        Ya_i, Yb_u, hU, rowBEU, listsU, bnS, bnB, N_U, aU,
        Ya_u, Yb_i, hI, rowBEI, listsI, N_I);

    // ---- layer 1: Yi8 = hI @ Wl1 (only live I-half; reuses Yb_i) ----
    gemmI_kernel<<<gI, 256, 0, stream>>>(hI, pL1a, Yb_i, N_I);

    // ---- layer 1: U-side agg only -> bf16 aggU (reuses Yb_u) ----
    gather1agg_kernel<<<aU, 256, 0, stream>>>(Yb_i, Yb_u, rowBEU, listsU, N_U);

    // ---- tail: hU@(Wr1+I) + Agg -> foldedBN -> relu -> out1; @Wh+bh -> out0 ----
    tail_kernel<<<gU, 256, 0, stream>>>(
        hU, pL1b, Yb_u, bnS + 256, bnB + 256, pH, bh, out, out1, N_U);
}